// Round 12
// baseline (148.840 us; speedup 1.0000x reference)
//
#include <hip/hip_runtime.h>
#include <hip/hip_fp16.h>

// GAT: B=2, N=4096, F=512, H=8, d=o=64, alpha=0.2
// out[b,n,h*64+c] = elu( sum_m softmax_m(lrelu(f[n]+g[m])) * Wh[m,c] )
// Factorized scores p = max(Ef[n]*Eg[m], Ff[n]*Fg[m]) (all in (0,1], fp16,
// zero transcendentals in O(N^2)). Denominator via v_dot2_f32_f16.
// r12: TLP synthesis. Invariant r8-r11: VALU-busy ~21us, MFMA-busy ~14us
// regardless of structure; ILP attempts fail (compiler sinks loads, r11
// VGPR=76 proves it). Untried corner: 4 waves/SIMD + 256MB traffic +
// 16-MFMA prefetch lead = 512-thr blocks, 4kg(disjoint m) x 2wr, packed-B
// direct-from-L2, depth-1 ping-pong. Epilogue = r4's verified 3-round
// kg-reduction. launch_bounds(512,4); r7 proved this tile fits 64 VGPR.

#define NB   2
#define NN   4096
#define NH   8
#define ALPHA 0.2f
#define LOG2E 1.4426950408889634f

typedef _Float16 f16x8 __attribute__((ext_vector_type(8)));
typedef _Float16 f16x2 __attribute__((ext_vector_type(2)));
typedef float    f32x4 __attribute__((ext_vector_type(4)));

__device__ __forceinline__ float dot2acc(f16x2 a, f16x2 b, float c) {
#if __has_builtin(__builtin_amdgcn_fdot2)
    return __builtin_amdgcn_fdot2(a, b, c, false);
#else
    return c + (float)a[0] * (float)b[0] + (float)a[1] * (float)b[1];
#endif
}

// ---------------------------------------------------------------------------
// Kernel 1: per (b,h), 64-row tile: Wh = h_tile @ W[h]  (fp32 vector GEMM)
// Outputs: Wh PACKED in B-fragment order:
//   P[bh][ms(128)][ct(4)][l(64)][h(8)] = Wh[m=ms*32+(l>>4)*8+h][c=ct*16+(l&15)]
// plus f'=(Wh.a1)*log2e, g'=(Wh.a2)*log2e.
// ---------------------------------------------------------------------------
__global__ __launch_bounds__(256) void k_wh(
    const float* __restrict__ hsrc, const float* __restrict__ W,
    const float* __restrict__ a,
    _Float16* __restrict__ Wh_p, float* __restrict__ fb, float* __restrict__ gb)
{
    const int bid  = blockIdx.x;
    const int tile = bid & 63;
    const int bh   = bid >> 6;
    const int hh   = bh & 7;
    const int b    = bh >> 3;
    const int n0   = tile * 64;
    const int t    = threadIdx.x;

    __shared__ float Wl[64 * 68];   // [k][c] pad 68 (272B rows, 16B aligned)
    __shared__ float ht[64 * 68];   // [r][k] pad 68; reused as fp16 wt[c][72]
    __shared__ float red[2 * 64 * 16];

    {
        const float* Wg = W + hh * 4096;
        #pragma unroll
        for (int p = 0; p < 4; p++) {
            int idx = (t + p * 256) * 4;
            float4 v = *(const float4*)(Wg + idx);
            int k = idx >> 6, c = idx & 63;
            *(float4*)(&Wl[k * 68 + c]) = v;
        }
    }
    {
        #pragma unroll
        for (int p = 0; p < 4; p++) {
            int idx = t + p * 256;
            int r = idx >> 4, kq = (idx & 15) * 4;
            float4 v = *(const float4*)(hsrc + ((size_t)(b * NN + n0 + r)) * 512 + hh * 64 + kq);
            *(float4*)(&ht[r * 68 + kq]) = v;
        }
    }
    __syncthreads();

    const int rq = t >> 4, cq = t & 15;
    float acc[4][4] = {};
    for (int k4 = 0; k4 < 64; k4 += 4) {
        float4 hv[4], wv[4];
        #pragma unroll
        for (int i = 0; i < 4; i++) hv[i] = *(const float4*)(&ht[(rq * 4 + i) * 68 + k4]);
        #pragma unroll
        for (int kk = 0; kk < 4; kk++) wv[kk] = *(const float4*)(&Wl[(k4 + kk) * 68 + cq * 4]);
        #pragma unroll
        for (int i = 0; i < 4; i++) {
            const float* hp = (const float*)&hv[i];
            #pragma unroll
            for (int kk = 0; kk < 4; kk++) {
                const float* wp = (const float*)&wv[kk];
                #pragma unroll
                for (int j = 0; j < 4; j++)
                    acc[i][j] = fmaf(hp[kk], wp[j], acc[i][j]);
            }
        }
    }

    float a1v[4], a2v[4];
    {
        const float* ag = a + hh * 128;
        #pragma unroll
        for (int j = 0; j < 4; j++) { a1v[j] = ag[cq * 4 + j]; a2v[j] = ag[64 + cq * 4 + j]; }
    }
    __syncthreads();

    // wt[c][n_local], row stride 72 halves: packed-read below is 2-way bank
    // aliased (free) instead of 16-way at stride 64.
    _Float16* wt = (_Float16*)ht;
    #pragma unroll
    for (int i = 0; i < 4; i++) {
        float fp = 0.f, gp = 0.f;
        #pragma unroll
        for (int j = 0; j < 4; j++) {
            fp = fmaf(acc[i][j], a1v[j], fp);
            gp = fmaf(acc[i][j], a2v[j], gp);
        }
        red[0 * 1024 + (rq * 4 + i) * 16 + cq] = fp;
        red[1 * 1024 + (rq * 4 + i) * 16 + cq] = gp;
        #pragma unroll
        for (int j = 0; j < 4; j++)
            wt[(cq * 4 + j) * 72 + rq * 4 + i] = (_Float16)acc[i][j];
    }
    __syncthreads();

    if (t < 128) {
        int which = t >> 6, row = t & 63;
        const float* rr = &red[which * 1024 + row * 16];
        float s = 0.f;
        #pragma unroll
        for (int j = 0; j < 16; j++) s += rr[j];
        s *= LOG2E;
        float* dst = which ? gb : fb;
        dst[(size_t)bh * NN + n0 + row] = s;
    }

    // packed fragment write: this tile covers ms = tile*2 + {0,1}
    #pragma unroll
    for (int p = 0; p < 2; p++) {
        int idx = t + p * 256;           // 0..511
        int ms  = idx >> 8;              // 0..1
        int ct  = (idx >> 6) & 3;        // 0..3
        int l   = idx & 63;              // lane slot
        f16x8 v = *(const f16x8*)(&wt[(ct * 16 + (l & 15)) * 72 + ms * 32 + (l >> 4) * 8]);
        *(f16x8*)(Wh_p + (size_t)bh * 64 * NN
                       + (((size_t)(tile * 2 + ms) * 4 + ct) * 64 + l) * 8) = v;
    }
}

// ---------------------------------------------------------------------------
// Kernel prep: per bh: G = max g'; Eg = 2^(g-G), Fg = 2^(alpha*(g-G)) fp16.
// Eg/Fg ALIAS the g storage: all g reads into regs before aliased writes.
// ---------------------------------------------------------------------------
__global__ __launch_bounds__(256) void k_prep(const float* __restrict__ gball,
                                              float* __restrict__ G,
                                              char* __restrict__ egfg_base)
{
    int bh = blockIdx.x, t = threadIdx.x;
    const float* g = gball + (size_t)bh * NN;
    float vals[16];
    float m = -1e30f;
    #pragma unroll
    for (int j = 0; j < 16; j++) { vals[j] = g[t + j * 256]; m = fmaxf(m, vals[j]); }
    #pragma unroll
    for (int s = 1; s < 64; s <<= 1) m = fmaxf(m, __shfl_xor(m, s, 64));
    __shared__ float wm[4];
    if ((t & 63) == 0) wm[t >> 6] = m;
    __syncthreads();
    float Gv = fmaxf(fmaxf(wm[0], wm[1]), fmaxf(wm[2], wm[3]));
    if (t == 0) G[bh] = Gv;
    _Float16* Eg = (_Float16*)(egfg_base + (size_t)bh * 16384);
    _Float16* Fg = Eg + NN;
    #pragma unroll
    for (int j = 0; j < 16; j++) {
        int i = t + j * 256;
        float d = vals[j] - Gv;
        Eg[i] = (_Float16)exp2f(d);
        Fg[i] = (_Float16)exp2f(ALPHA * d);
    }
}

// ---------------------------------------------------------------------------
// Kernel 2: attention. 512 blocks x 512 thr. Block: 128 rows x 64 cols.
// Wave w: kg=w>>1 (m-range kg*1024..+1024, DISJOINT -> block traffic stays
// 512KB), wr=w&1 (rows wr*64..+64). Wave tile: 64 rows (4 rg) x 64 cols
// (4 ct) x 1024 m (32 half-steps of 32). Packed-B lane-contiguous 1KB
// bursts; depth-1 register ping-pong; 16-MFMA lead per load set; 16 waves/CU.
// Epilogue: r4's verified 3-round kg-reduction through LDS.
// ---------------------------------------------------------------------------
__global__ __launch_bounds__(512, 4) void k_attn(
    const _Float16* __restrict__ Wh_p, const float* __restrict__ fb,
    const float* __restrict__ G, const char* __restrict__ egfg_base,
    float* __restrict__ out)
{
    // XCD-bijective swizzle: 512 = 8 XCD x 64; XCD x owns 2 full bh slices.
    const int orig  = blockIdx.x;
    const int bid   = (orig & 7) * 64 + (orig >> 3);
    const int ntile = bid & 31;
    const int bh    = bid >> 5;
    const int hh    = bh & 7;
    const int b     = bh >> 3;
    const int n0    = ntile * 128;
    const int t     = threadIdx.x;
    const int w     = t >> 6;
    const int l     = t & 63;
    const int kg    = w >> 1;        // 0..3 m-split (disjoint ranges)
    const int wr    = w & 1;         // 0..1 row-split
    const int lr    = l & 15;
    const int lg    = l >> 4;

    const _Float16* Pp  = Wh_p + (size_t)bh * 64 * NN;
    const _Float16* Egp = (const _Float16*)(egfg_base + (size_t)bh * 16384);
    const float     Gv  = G[bh];

    // per-row factors (one of Ef,Ff is exactly 1)
    f16x2 ef2[4], ff2[4];
    #pragma unroll
    for (int rg = 0; rg < 4; rg++) {
        int rn = n0 + wr * 64 + rg * 16 + lr;
        float s  = fb[(size_t)bh * NN + rn] + Gv;
        float t1 = (1.f - ALPHA) * s;
        _Float16 e = (_Float16)exp2f(fminf(t1, 0.f));
        _Float16 f = (_Float16)exp2f(fminf(-t1, 0.f));
        ef2[rg] = (f16x2){e, e};
        ff2[rg] = (f16x2){f, f};
    }
    const f16x2 one2 = (f16x2){(_Float16)1.0f, (_Float16)1.0f};

    f32x4 acc[4][4];
    #pragma unroll
    for (int rg = 0; rg < 4; rg++)
        #pragma unroll
        for (int ct = 0; ct < 4; ct++) acc[rg][ct] = (f32x4){0.f, 0.f, 0.f, 0.f};
    float dsum[4] = {0.f, 0.f, 0.f, 0.f};

    // packed B pointer: one ms-chunk = 2048 halves; kg owns 32 chunks
    const _Float16* bp  = Pp + (size_t)kg * 32 * 2048 + (size_t)l * 8;
    const _Float16* ep  = Egp + kg * 1024 + lg * 8;
    const _Float16* epf = ep + NN;

    #define LOADSET(B0,B1,B2,B3,EG,FG)                                          \
        {                                                                        \
            B0 = *(const f16x8*)(bp);         B1 = *(const f16x8*)(bp + 512);    \
            B2 = *(const f16x8*)(bp + 1024);  B3 = *(const f16x8*)(bp + 1536);   \
            EG = *(const f16x8*)ep;           FG = *(const f16x8*)epf;           \
            bp += 2048; ep += 32; epf += 32;                                     \
        }

    #define COMPUTE(B0,B1,B2,B3,EG,FG)                                          \
        {                                                                        \
            _Pragma("unroll")                                                    \
            for (int rg = 0; rg < 4; rg++) {                                     \
                f16x8 af; float ds = dsum[rg];                                   \
                _Pragma("unroll")                                                \
                for (int d = 0; d < 4; d++) {                                    \
                    f16x2 e2 = ((const f16x2*)&(EG))[d];                         \
                    f16x2 f2 = ((const f16x2*)&(FG))[d];                         \
                    f16x2 p2 = __builtin_elementwise_max(e2 * ef2[rg],           \
                                                         f2 * ff2[rg]);          \
                    ((f16x2*)&af)[d] = p2;                                       \
                    ds = dot2acc(p2, one2, ds);                                  \
                }                                                                \
                dsum[rg] = ds;                                                   \
                acc[rg][0] = __builtin_amdgcn_mfma_f32_16x16x32_f16(             \
                    af, B0, acc[rg][0], 0, 0, 0);                                \
                acc[rg][1] = __builtin_amdgcn_mfma_f32_16x16x32_f16(             \
                    af, B1, acc[rg][1], 0, 0, 0);                                \
                acc[rg][2] = __builtin_amdgcn_mfma_f32_16x16x32_f16(             \
                    af, B2, acc[rg][2], 0, 0, 0);                                \
                acc[rg][3] = __builtin_amdgcn_mfma_f32_16x16x32_f16(             \
                    af, B3, acc[rg][3], 0, 0, 0);                                \
            }                                                                    \
        }

    f16x8 a0, a1, a2, a3, ae, az;
    f16x8 c0, c1, c2, c3, ce, cz;
    LOADSET(a0, a1, a2, a3, ae, az);

    // 32 half-steps of 32 m; depth-1 ping-pong (loads issued one full
    // 16-MFMA COMPUTE phase before use).
    #pragma clang loop unroll(disable)
    for (int hs = 0; hs < 32; hs += 2) {
        LOADSET(c0, c1, c2, c3, ce, cz);
        COMPUTE(a0, a1, a2, a3, ae, az);
        if (hs + 2 < 32) LOADSET(a0, a1, a2, a3, ae, az);
        COMPUTE(c0, c1, c2, c3, ce, cz);
    }
    #undef LOADSET
    #undef COMPUTE

    // ---------------- epilogue: 3-round kg-reduction (r4-verified) ---------
    __shared__ f32x4 __attribute__((aligned(16))) Rw[2][16 * 64];  // 32 KB
    __shared__ float dnP[512];
    __shared__ float dnS[128];

    // per-row denominator partials (reduce lg groups in-wave)
    #pragma unroll
    for (int rg = 0; rg < 4; rg++) {
        float d = dsum[rg];
        d += __shfl_xor(d, 16, 64);
        d += __shfl_xor(d, 32, 64);
        if (lg == 0) dnP[kg * 128 + wr * 64 + rg * 16 + lr] = d;
    }

    #define WRITE_R()                                                            \
        { _Pragma("unroll") for (int rg = 0; rg < 4; rg++)                       \
          _Pragma("unroll") for (int ct = 0; ct < 4; ct++)                       \
            Rw[wr][(rg * 4 + ct) * 64 + l] = acc[rg][ct]; }
    #define ADD_R()                                                              \
        { _Pragma("unroll") for (int rg = 0; rg < 4; rg++)                       \
          _Pragma("unroll") for (int ct = 0; ct < 4; ct++)                       \
            acc[rg][ct] += Rw[wr][(rg * 4 + ct) * 64 + l]; }

    if (kg == 1) WRITE_R();
    __syncthreads();
    if (t < 128) dnS[t] = dnP[t] + dnP[128 + t] + dnP[256 + t] + dnP[384 + t];
    if (kg == 0) ADD_R();
    __syncthreads();
    if (kg == 2) WRITE_R();
    __syncthreads();
    if (kg == 0) ADD_R();
    __syncthreads();
    if (kg == 3) WRITE_R();
    __syncthreads();

    if (kg == 0) {
        ADD_R();
        float* outp = out + ((size_t)(b * NN + n0)) * 512 + hh * 64;
        #pragma unroll
        for (int rg = 0; rg < 4; rg++)
            #pragma unroll
            for (int reg = 0; reg < 4; reg++) {
                int row = wr * 64 + rg * 16 + lg * 4 + reg;
                float rinv = 1.0f / dnS[row];
                #pragma unroll
                for (int ct = 0; ct < 4; ct++) {
                    float v = acc[rg][ct][reg] * rinv;
                    v = v > 0.f ? v : (exp2f(v * LOG2E) - 1.f);   // elu
                    outp[(size_t)row * 512 + ct * 16 + lr] = v;
                }
            }
    }
    #undef WRITE_R
    #undef ADD_R
}

// ---------------------------------------------------------------------------
extern "C" void kernel_launch(void* const* d_in, const int* in_sizes, int n_in,
                              void* d_out, int out_size, void* d_ws, size_t ws_size,
                              hipStream_t stream)
{
    const float* hsrc = (const float*)d_in[0];
    const float* W    = (const float*)d_in[1];
    const float* a    = (const float*)d_in[2];
    float* outp       = (float*)d_out;

    const size_t WHT_BYTES = (size_t)NB * NH * 64 * NN * sizeof(_Float16); // 8 MB
    const size_t FB_BYTES  = (size_t)NB * NH * NN * sizeof(float);         // 256 KB
    const size_t GB_BYTES  = (size_t)NB * NH * NN * sizeof(float);         // 256 KB
    const size_t NEED = WHT_BYTES + FB_BYTES + GB_BYTES + 64 * sizeof(float);
    if (ws_size < NEED) return;

    char* ws = (char*)d_ws;
    _Float16* Wh_p = (_Float16*)ws;
    float*    fbuf = (float*)(ws + WHT_BYTES);
    char*     gbase = ws + WHT_BYTES + FB_BYTES;   // g' f32 -> Eg|Fg fp16 (aliased)
    float*    Gmax = (float*)(ws + WHT_BYTES + FB_BYTES + GB_BYTES);

    k_wh  <<<dim3(NB * NH * (NN / 64)),  dim3(256), 0, stream>>>(hsrc, W, a, Wh_p, fbuf, (float*)gbase);
    k_prep<<<dim3(NB * NH),              dim3(256), 0, stream>>>((const float*)gbase, Gmax, gbase);
    k_attn<<<dim3(NB * NH * (NN / 128)), dim3(512), 0, stream>>>(Wh_p, fbuf, Gmax, gbase, outp);
}

// Round 13
// 70.448 us; speedup vs baseline: 2.1128x; 2.1128x over previous
//
#include <hip/hip_runtime.h>
#include <hip/hip_fp16.h>

// GAT: B=2, N=4096, F=512, H=8, d=o=64, alpha=0.2
// out[b,n,h*64+c] = elu( sum_m softmax_m(lrelu(f[n]+g[m])) * Wh[m,c] )
// Factorized scores p = max(Ef[n]*Eg[m], Ff[n]*Fg[m]) (all in (0,1], fp16,
// zero transcendentals in O(N^2)). Denominator via v_dot2_f32_f16.
// r13 = r7's register-frugal structure (512 thr, 4kg x 2wr, SERIAL loads --
// proven 64 VGPR / no spill at (512,4)) + r9's PACKED coalesced B loads
// (lane-contiguous 1KB bursts). r12's ping-pong spilled (+24 VGPR over the
// 128 budget, WRITE 292MB); r11 proved manual ILP gets undone by the
// compiler; so latency is hidden by TLP alone: 4 waves/SIMD, required
// cover (174+300)/174 ~= 2.7 < 4. Epilogue: r4-verified 3-round reduction.

#define NB   2
#define NN   4096
#define NH   8
#define ALPHA 0.2f
#define LOG2E 1.4426950408889634f

typedef _Float16 f16x8 __attribute__((ext_vector_type(8)));
typedef _Float16 f16x2 __attribute__((ext_vector_type(2)));
typedef float    f32x4 __attribute__((ext_vector_type(4)));

__device__ __forceinline__ float dot2acc(f16x2 a, f16x2 b, float c) {
#if __has_builtin(__builtin_amdgcn_fdot2)
    return __builtin_amdgcn_fdot2(a, b, c, false);
#else
    return c + (float)a[0] * (float)b[0] + (float)a[1] * (float)b[1];
#endif
}

// ---------------------------------------------------------------------------
// Kernel 1: per (b,h), 64-row tile: Wh = h_tile @ W[h]  (fp32 vector GEMM)
// Outputs: Wh PACKED in B-fragment order:
//   P[bh][ms(128)][ct(4)][l(64)][h(8)] = Wh[m=ms*32+(l>>4)*8+h][c=ct*16+(l&15)]
// plus f'=(Wh.a1)*log2e, g'=(Wh.a2)*log2e.
// ---------------------------------------------------------------------------
__global__ __launch_bounds__(256) void k_wh(
    const float* __restrict__ hsrc, const float* __restrict__ W,
    const float* __restrict__ a,
    _Float16* __restrict__ Wh_p, float* __restrict__ fb, float* __restrict__ gb)
{
    const int bid  = blockIdx.x;
    const int tile = bid & 63;
    const int bh   = bid >> 6;
    const int hh   = bh & 7;
    const int b    = bh >> 3;
    const int n0   = tile * 64;
    const int t    = threadIdx.x;

    __shared__ float Wl[64 * 68];   // [k][c] pad 68 (272B rows, 16B aligned)
    __shared__ float ht[64 * 68];   // [r][k] pad 68; reused as fp16 wt[c][72]
    __shared__ float red[2 * 64 * 16];

    {
        const float* Wg = W + hh * 4096;
        #pragma unroll
        for (int p = 0; p < 4; p++) {
            int idx = (t + p * 256) * 4;
            float4 v = *(const float4*)(Wg + idx);
            int k = idx >> 6, c = idx & 63;
            *(float4*)(&Wl[k * 68 + c]) = v;
        }
    }
    {
        #pragma unroll
        for (int p = 0; p < 4; p++) {
            int idx = t + p * 256;
            int r = idx >> 4, kq = (idx & 15) * 4;
            float4 v = *(const float4*)(hsrc + ((size_t)(b * NN + n0 + r)) * 512 + hh * 64 + kq);
            *(float4*)(&ht[r * 68 + kq]) = v;
        }
    }
    __syncthreads();

    const int rq = t >> 4, cq = t & 15;
    float acc[4][4] = {};
    for (int k4 = 0; k4 < 64; k4 += 4) {
        float4 hv[4], wv[4];
        #pragma unroll
        for (int i = 0; i < 4; i++) hv[i] = *(const float4*)(&ht[(rq * 4 + i) * 68 + k4]);
        #pragma unroll
        for (int kk = 0; kk < 4; kk++) wv[kk] = *(const float4*)(&Wl[(k4 + kk) * 68 + cq * 4]);
        #pragma unroll
        for (int i = 0; i < 4; i++) {
            const float* hp = (const float*)&hv[i];
            #pragma unroll
            for (int kk = 0; kk < 4; kk++) {
                const float* wp = (const float*)&wv[kk];
                #pragma unroll
                for (int j = 0; j < 4; j++)
                    acc[i][j] = fmaf(hp[kk], wp[j], acc[i][j]);
            }
        }
    }

    float a1v[4], a2v[4];
    {
        const float* ag = a + hh * 128;
        #pragma unroll
        for (int j = 0; j < 4; j++) { a1v[j] = ag[cq * 4 + j]; a2v[j] = ag[64 + cq * 4 + j]; }
    }
    __syncthreads();

    // wt[c][n_local], row stride 72 halves: packed-read below is 2-way bank
    // aliased (free) instead of 16-way at stride 64.
    _Float16* wt = (_Float16*)ht;
    #pragma unroll
    for (int i = 0; i < 4; i++) {
        float fp = 0.f, gp = 0.f;
        #pragma unroll
        for (int j = 0; j < 4; j++) {
            fp = fmaf(acc[i][j], a1v[j], fp);
            gp = fmaf(acc[i][j], a2v[j], gp);
        }
        red[0 * 1024 + (rq * 4 + i) * 16 + cq] = fp;
        red[1 * 1024 + (rq * 4 + i) * 16 + cq] = gp;
        #pragma unroll
        for (int j = 0; j < 4; j++)
            wt[(cq * 4 + j) * 72 + rq * 4 + i] = (_Float16)acc[i][j];
    }
    __syncthreads();

    if (t < 128) {
        int which = t >> 6, row = t & 63;
        const float* rr = &red[which * 1024 + row * 16];
        float s = 0.f;
        #pragma unroll
        for (int j = 0; j < 16; j++) s += rr[j];
        s *= LOG2E;
        float* dst = which ? gb : fb;
        dst[(size_t)bh * NN + n0 + row] = s;
    }

    // packed fragment write: this tile covers ms = tile*2 + {0,1}
    #pragma unroll
    for (int p = 0; p < 2; p++) {
        int idx = t + p * 256;           // 0..511
        int ms  = idx >> 8;              // 0..1
        int ct  = (idx >> 6) & 3;        // 0..3
        int l   = idx & 63;              // lane slot
        f16x8 v = *(const f16x8*)(&wt[(ct * 16 + (l & 15)) * 72 + ms * 32 + (l >> 4) * 8]);
        *(f16x8*)(Wh_p + (size_t)bh * 64 * NN
                       + (((size_t)(tile * 2 + ms) * 4 + ct) * 64 + l) * 8) = v;
    }
}

// ---------------------------------------------------------------------------
// Kernel prep: per bh: G = max g'; Eg = 2^(g-G), Fg = 2^(alpha*(g-G)) fp16.
// Eg/Fg ALIAS the g storage: all g reads into regs before aliased writes.
// ---------------------------------------------------------------------------
__global__ __launch_bounds__(256) void k_prep(const float* __restrict__ gball,
                                              float* __restrict__ G,
                                              char* __restrict__ egfg_base)
{
    int bh = blockIdx.x, t = threadIdx.x;
    const float* g = gball + (size_t)bh * NN;
    float vals[16];
    float m = -1e30f;
    #pragma unroll
    for (int j = 0; j < 16; j++) { vals[j] = g[t + j * 256]; m = fmaxf(m, vals[j]); }
    #pragma unroll
    for (int s = 1; s < 64; s <<= 1) m = fmaxf(m, __shfl_xor(m, s, 64));
    __shared__ float wm[4];
    if ((t & 63) == 0) wm[t >> 6] = m;
    __syncthreads();
    float Gv = fmaxf(fmaxf(wm[0], wm[1]), fmaxf(wm[2], wm[3]));
    if (t == 0) G[bh] = Gv;
    _Float16* Eg = (_Float16*)(egfg_base + (size_t)bh * 16384);
    _Float16* Fg = Eg + NN;
    #pragma unroll
    for (int j = 0; j < 16; j++) {
        int i = t + j * 256;
        float d = vals[j] - Gv;
        Eg[i] = (_Float16)exp2f(d);
        Fg[i] = (_Float16)exp2f(ALPHA * d);
    }
}

// ---------------------------------------------------------------------------
// Kernel 2: attention. 512 blocks x 512 thr. Block: 128 rows x 64 cols.
// Wave w: kg=w>>1 (m-range kg*1024..+1024, DISJOINT -> block traffic stays
// 512KB), wr=w&1 (rows wr*64..+64). Wave tile: 64 rows (4 rg) x 64 cols
// (4 ct) x 1024 m (32 half-steps of 32). Packed-B lane-contiguous 1KB
// bursts, SERIAL per-hs loads (r7-proven 64-VGPR codegen; TLP hides L2
// latency at 4 waves/SIMD). Epilogue: r4-verified 3-round kg-reduction.
// ---------------------------------------------------------------------------
__global__ __launch_bounds__(512, 4) void k_attn(
    const _Float16* __restrict__ Wh_p, const float* __restrict__ fb,
    const float* __restrict__ G, const char* __restrict__ egfg_base,
    float* __restrict__ out)
{
    // XCD-bijective swizzle: 512 = 8 XCD x 64; XCD x owns 2 full bh slices.
    const int orig  = blockIdx.x;
    const int bid   = (orig & 7) * 64 + (orig >> 3);
    const int ntile = bid & 31;
    const int bh    = bid >> 5;
    const int hh    = bh & 7;
    const int b     = bh >> 3;
    const int n0    = ntile * 128;
    const int t     = threadIdx.x;
    const int w     = t >> 6;
    const int l     = t & 63;
    const int kg    = w >> 1;        // 0..3 m-split (disjoint ranges)
    const int wr    = w & 1;         // 0..1 row-split
    const int lr    = l & 15;
    const int lg    = l >> 4;

    const _Float16* Pp  = Wh_p + (size_t)bh * 64 * NN;
    const _Float16* Egp = (const _Float16*)(egfg_base + (size_t)bh * 16384);
    const float     Gv  = G[bh];

    // per-row factors (one of Ef,Ff is exactly 1)
    f16x2 ef2[4], ff2[4];
    #pragma unroll
    for (int rg = 0; rg < 4; rg++) {
        int rn = n0 + wr * 64 + rg * 16 + lr;
        float s  = fb[(size_t)bh * NN + rn] + Gv;
        float t1 = (1.f - ALPHA) * s;
        _Float16 e = (_Float16)exp2f(fminf(t1, 0.f));
        _Float16 f = (_Float16)exp2f(fminf(-t1, 0.f));
        ef2[rg] = (f16x2){e, e};
        ff2[rg] = (f16x2){f, f};
    }
    const f16x2 one2 = (f16x2){(_Float16)1.0f, (_Float16)1.0f};

    f32x4 acc[4][4];
    #pragma unroll
    for (int rg = 0; rg < 4; rg++)
        #pragma unroll
        for (int ct = 0; ct < 4; ct++) acc[rg][ct] = (f32x4){0.f, 0.f, 0.f, 0.f};
    float dsum[4] = {0.f, 0.f, 0.f, 0.f};

    // packed B pointer: one ms-chunk = 2048 halves; kg owns 32 chunks
    const _Float16* bp  = Pp + (size_t)kg * 32 * 2048 + (size_t)l * 8;
    const _Float16* ep  = Egp + kg * 1024 + lg * 8;
    const _Float16* epf = ep + NN;

    // 32 half-steps of 32 m; serial loads (compiler schedules the 6
    // outstanding loads; TLP across 4 waves/SIMD hides L2 latency).
    #pragma clang loop unroll(disable)
    for (int hs = 0; hs < 32; hs++) {
        f16x8 b0  = *(const f16x8*)(bp);
        f16x8 b1  = *(const f16x8*)(bp + 512);
        f16x8 b2  = *(const f16x8*)(bp + 1024);
        f16x8 b3  = *(const f16x8*)(bp + 1536);
        f16x8 eg8 = *(const f16x8*)ep;
        f16x8 fg8 = *(const f16x8*)epf;
        bp += 2048; ep += 32; epf += 32;

        #pragma unroll
        for (int rg = 0; rg < 4; rg++) {
            f16x8 af; float ds = dsum[rg];
            #pragma unroll
            for (int d = 0; d < 4; d++) {
                f16x2 e2 = ((const f16x2*)&eg8)[d];
                f16x2 f2 = ((const f16x2*)&fg8)[d];
                f16x2 p2 = __builtin_elementwise_max(e2 * ef2[rg], f2 * ff2[rg]);
                ((f16x2*)&af)[d] = p2;
                ds = dot2acc(p2, one2, ds);
            }
            dsum[rg] = ds;
            acc[rg][0] = __builtin_amdgcn_mfma_f32_16x16x32_f16(af, b0, acc[rg][0], 0, 0, 0);
            acc[rg][1] = __builtin_amdgcn_mfma_f32_16x16x32_f16(af, b1, acc[rg][1], 0, 0, 0);
            acc[rg][2] = __builtin_amdgcn_mfma_f32_16x16x32_f16(af, b2, acc[rg][2], 0, 0, 0);
            acc[rg][3] = __builtin_amdgcn_mfma_f32_16x16x32_f16(af, b3, acc[rg][3], 0, 0, 0);
        }
    }

    // ---------------- epilogue: 3-round kg-reduction (r4-verified) ---------
    __shared__ f32x4 __attribute__((aligned(16))) Rw[2][16 * 64];  // 32 KB
    __shared__ float dnP[512];
    __shared__ float dnS[128];

    // per-row denominator partials (reduce lg groups in-wave)
    #pragma unroll
    for (int rg = 0; rg < 4; rg++) {
        float d = dsum[rg];
        d += __shfl_xor(d, 16, 64);
        d += __shfl_xor(d, 32, 64);
        if (lg == 0) dnP[kg * 128 + wr * 64 + rg * 16 + lr] = d;
    }

    #define WRITE_R()                                                            \
        { _Pragma("unroll") for (int rg = 0; rg < 4; rg++)                       \
          _Pragma("unroll") for (int ct = 0; ct < 4; ct++)                       \
            Rw[wr][(rg * 4 + ct) * 64 + l] = acc[rg][ct]; }
    #define ADD_R()                                                              \
        { _Pragma("unroll") for (int rg = 0; rg < 4; rg++)                       \
          _Pragma("unroll") for (int ct = 0; ct < 4; ct++)                       \
            acc[rg][ct] += Rw[wr][(rg * 4 + ct) * 64 + l]; }

    if (kg == 1) WRITE_R();
    __syncthreads();
    if (t < 128) dnS[t] = dnP[t] + dnP[128 + t] + dnP[256 + t] + dnP[384 + t];
    if (kg == 0) ADD_R();
    __syncthreads();
    if (kg == 2) WRITE_R();
    __syncthreads();
    if (kg == 0) ADD_R();
    __syncthreads();
    if (kg == 3) WRITE_R();
    __syncthreads();

    if (kg == 0) {
        ADD_R();
        float* outp = out + ((size_t)(b * NN + n0)) * 512 + hh * 64;
        #pragma unroll
        for (int rg = 0; rg < 4; rg++)
            #pragma unroll
            for (int reg = 0; reg < 4; reg++) {
                int row = wr * 64 + rg * 16 + lg * 4 + reg;
                float rinv = 1.0f / dnS[row];
                #pragma unroll
                for (int ct = 0; ct < 4; ct++) {
                    float v = acc[rg][ct][reg] * rinv;
                    v = v > 0.f ? v : (exp2f(v * LOG2E) - 1.f);   // elu
                    outp[(size_t)row * 512 + ct * 16 + lr] = v;
                }
            }
    }
    #undef WRITE_R
    #undef ADD_R
}

// ---------------------------------------------------------------------------
extern "C" void kernel_launch(void* const* d_in, const int* in_sizes, int n_in,
                              void* d_out, int out_size, void* d_ws, size_t ws_size,
                              hipStream_t stream)
{
    const float* hsrc = (const float*)d_in[0];
    const float* W    = (const float*)d_in[1];
    const float* a    = (const float*)d_in[2];
    float* outp       = (float*)d_out;

    const size_t WHT_BYTES = (size_t)NB * NH * 64 * NN * sizeof(_Float16); // 8 MB
    const size_t FB_BYTES  = (size_t)NB * NH * NN * sizeof(float);         // 256 KB
    const size_t GB_BYTES  = (size_t)NB * NH * NN * sizeof(float);         // 256 KB
    const size_t NEED = WHT_BYTES + FB_BYTES + GB_BYTES + 64 * sizeof(float);
    if (ws_size < NEED) return;

    char* ws = (char*)d_ws;
    _Float16* Wh_p = (_Float16*)ws;
    float*    fbuf = (float*)(ws + WHT_BYTES);
    char*     gbase = ws + WHT_BYTES + FB_BYTES;   // g' f32 -> Eg|Fg fp16 (aliased)
    float*    Gmax = (float*)(ws + WHT_BYTES + FB_BYTES + GB_BYTES);

    k_wh  <<<dim3(NB * NH * (NN / 64)),  dim3(256), 0, stream>>>(hsrc, W, a, Wh_p, fbuf, (float*)gbase);
    k_prep<<<dim3(NB * NH),              dim3(256), 0, stream>>>((const float*)gbase, Gmax, gbase);
    k_attn<<<dim3(NB * NH * (NN / 128)), dim3(512), 0, stream>>>(Wh_p, fbuf, Gmax, gbase, outp);
}

// Round 14
// 56.914 us; speedup vs baseline: 2.6152x; 1.2378x over previous
//
#include <hip/hip_runtime.h>
#include <hip/hip_fp16.h>

// GAT: B=2, N=4096, F=512, H=8, d=o=64, alpha=0.2
// out[b,n,h*64+c] = elu( sum_m softmax_m(lrelu(f[n]+g[m])) * Wh[m,c] )
// Factorized scores p = max(Ef[n]*Eg[m], Ff[n]*Fg[m]) (all in (0,1], fp16,
// zero transcendentals in O(N^2)). Denominator via v_dot2_f32_f16.
// r14: k_attn = r9 VERBATIM (best measured: 48.3us; r10-r13 proved no
// scheduling variant beats it). k_wh rebuilt on MFMA: h cast to fp16
// (delta-Wh ~6e-4, below the existing 3e-3 Wh-storage rounding), A-frags
// straight from global h, B = W transposed once into LDS [c][88] fp16,
// 8 mfma_16x16x32_f16 per wave. Replaces ~15us of LDS/VALU with ~1us.

#define NB   2
#define NN   4096
#define NH   8
#define ALPHA 0.2f
#define LOG2E 1.4426950408889634f

typedef _Float16 f16x8 __attribute__((ext_vector_type(8)));
typedef _Float16 f16x2 __attribute__((ext_vector_type(2)));
typedef float    f32x4 __attribute__((ext_vector_type(4)));

__device__ __forceinline__ float dot2acc(f16x2 a, f16x2 b, float c) {
#if __has_builtin(__builtin_amdgcn_fdot2)
    return __builtin_amdgcn_fdot2(a, b, c, false);
#else
    return c + (float)a[0] * (float)b[0] + (float)a[1] * (float)b[1];
#endif
}

// ---------------------------------------------------------------------------
// Kernel 1 (MFMA version): per (b,h), 64-row tile: Wh = h_tile @ W[h].
// Wave w owns rows w*16..+15. A-frag (row=l&15, k=(l>>4)*8+j) loaded DIRECTLY
// from global h (rows contiguous) + cvt fp16. B staged once: W[k][c] read
// coalesced, written transposed fp16 to Wt16[c][88] (stride 88 halves ->
// ~2-way banks on b128 frag reads). D (row=(l>>4)*4+reg, col=l&15) -- the
// exact lane-maps k_attn verified end-to-end. Outputs: packed Wh_p,
// f'=(Wh.a1)*log2e, g'=(Wh.a2)*log2e.
// ---------------------------------------------------------------------------
__global__ __launch_bounds__(256) void k_wh(
    const float* __restrict__ hsrc, const float* __restrict__ W,
    const float* __restrict__ a,
    _Float16* __restrict__ Wh_p, float* __restrict__ fb, float* __restrict__ gb)
{
    const int bid  = blockIdx.x;
    const int tile = bid & 63;
    const int bh   = bid >> 6;
    const int hh   = bh & 7;
    const int b    = bh >> 3;
    const int n0   = tile * 64;
    const int t    = threadIdx.x;
    const int w    = t >> 6;
    const int l    = t & 63;
    const int lr   = l & 15;
    const int lg   = l >> 4;

    __shared__ _Float16 __attribute__((aligned(16))) Wt16[64 * 88]; // W^T [c][k]; reused as wt
    __shared__ float red[2 * 64 * 16];

    // --- stage W transposed: thread (c=t&63, kq=(t>>6)*16) reads W[k][c]
    //     coalesced (lanes = consecutive c) and writes fp16 [c][k].
    {
        const float* Wg = W + hh * 4096;
        const int c  = t & 63;
        const int kq = (t >> 6) * 16;
        #pragma unroll
        for (int j = 0; j < 16; j++)
            Wt16[c * 88 + kq + j] = (_Float16)Wg[(kq + j) * 64 + c];
    }

    // --- A-fragments from global h (before barrier; independent of LDS)
    const float* hrow = hsrc + ((size_t)(b * NN + n0 + w * 16 + lr)) * 512
                        + hh * 64 + lg * 8;
    f16x8 afr[2];
    #pragma unroll
    for (int kh = 0; kh < 2; kh++) {
        float4 u0 = *(const float4*)(hrow + kh * 32);
        float4 u1 = *(const float4*)(hrow + kh * 32 + 4);
        f16x8 v;
        v[0] = (_Float16)u0.x; v[1] = (_Float16)u0.y;
        v[2] = (_Float16)u0.z; v[3] = (_Float16)u0.w;
        v[4] = (_Float16)u1.x; v[5] = (_Float16)u1.y;
        v[6] = (_Float16)u1.z; v[7] = (_Float16)u1.w;
        afr[kh] = v;
    }
    __syncthreads();

    // --- MFMA: 8 per wave (2 kh x 4 ct)
    f32x4 acc[4];
    #pragma unroll
    for (int ct = 0; ct < 4; ct++) acc[ct] = (f32x4){0.f, 0.f, 0.f, 0.f};
    #pragma unroll
    for (int kh = 0; kh < 2; kh++)
        #pragma unroll
        for (int ct = 0; ct < 4; ct++) {
            f16x8 bfr = *(const f16x8*)(&Wt16[(ct * 16 + lr) * 88 + kh * 32 + lg * 8]);
            acc[ct] = __builtin_amdgcn_mfma_f32_16x16x32_f16(afr[kh], bfr, acc[ct], 0, 0, 0);
        }

    // --- f/g partials: lane holds rows w*16+lg*4+reg, cols ct*16+lr
    {
        float a1v[4], a2v[4];
        const float* ag = a + hh * 128;
        #pragma unroll
        for (int ct = 0; ct < 4; ct++) {
            a1v[ct] = ag[ct * 16 + lr];
            a2v[ct] = ag[64 + ct * 16 + lr];
        }
        #pragma unroll
        for (int reg = 0; reg < 4; reg++) {
            float fp = 0.f, gp = 0.f;
            #pragma unroll
            for (int ct = 0; ct < 4; ct++) {
                fp = fmaf(acc[ct][reg], a1v[ct], fp);
                gp = fmaf(acc[ct][reg], a2v[ct], gp);
            }
            int row = w * 16 + lg * 4 + reg;
            red[0 * 1024 + row * 16 + lr] = fp;
            red[1 * 1024 + row * 16 + lr] = gp;
        }
    }
    __syncthreads();                 // all B-frag reads done -> reuse Wt16 as wt

    // --- wt[c][row], stride 88 (aliases Wt16)
    _Float16* wt = Wt16;
    #pragma unroll
    for (int ct = 0; ct < 4; ct++)
        #pragma unroll
        for (int reg = 0; reg < 4; reg++)
            wt[(ct * 16 + lr) * 88 + w * 16 + lg * 4 + reg] = (_Float16)acc[ct][reg];
    __syncthreads();

    if (t < 128) {
        int which = t >> 6, row = t & 63;
        const float* rr = &red[which * 1024 + row * 16];
        float s = 0.f;
        #pragma unroll
        for (int j = 0; j < 16; j++) s += rr[j];
        s *= LOG2E;
        float* dst = which ? gb : fb;
        dst[(size_t)bh * NN + n0 + row] = s;
    }

    // packed fragment write: this tile covers ms = tile*2 + {0,1}
    #pragma unroll
    for (int p = 0; p < 2; p++) {
        int idx = t + p * 256;           // 0..511
        int ms  = idx >> 8;              // 0..1
        int ct  = (idx >> 6) & 3;        // 0..3
        int l2  = idx & 63;              // lane slot
        f16x8 v = *(const f16x8*)(&wt[(ct * 16 + (l2 & 15)) * 88 + ms * 32 + (l2 >> 4) * 8]);
        *(f16x8*)(Wh_p + (size_t)bh * 64 * NN
                       + (((size_t)(tile * 2 + ms) * 4 + ct) * 64 + l2) * 8) = v;
    }
}

// ---------------------------------------------------------------------------
// Kernel prep: per bh: G = max g'; Eg = 2^(g-G), Fg = 2^(alpha*(g-G)) fp16.
// Eg/Fg ALIAS the g storage: all g reads into regs before aliased writes.
// ---------------------------------------------------------------------------
__global__ __launch_bounds__(256) void k_prep(const float* __restrict__ gball,
                                              float* __restrict__ G,
                                              char* __restrict__ egfg_base)
{
    int bh = blockIdx.x, t = threadIdx.x;
    const float* g = gball + (size_t)bh * NN;
    float vals[16];
    float m = -1e30f;
    #pragma unroll
    for (int j = 0; j < 16; j++) { vals[j] = g[t + j * 256]; m = fmaxf(m, vals[j]); }
    #pragma unroll
    for (int s = 1; s < 64; s <<= 1) m = fmaxf(m, __shfl_xor(m, s, 64));
    __shared__ float wm[4];
    if ((t & 63) == 0) wm[t >> 6] = m;
    __syncthreads();
    float Gv = fmaxf(fmaxf(wm[0], wm[1]), fmaxf(wm[2], wm[3]));
    if (t == 0) G[bh] = Gv;
    _Float16* Eg = (_Float16*)(egfg_base + (size_t)bh * 16384);
    _Float16* Fg = Eg + NN;
    #pragma unroll
    for (int j = 0; j < 16; j++) {
        int i = t + j * 256;
        float d = vals[j] - Gv;
        Eg[i] = (_Float16)exp2f(d);
        Fg[i] = (_Float16)exp2f(ALPHA * d);
    }
}

// ---------------------------------------------------------------------------
// Kernel 2: attention (r9 VERBATIM). 512 blocks x 256 thr. Block: 128 rows x
// 64 cols. Wave w: kg=w>>1 (m-range kg*2048..+2048), wr=w&1 (rows wr*64..+64).
// B frags from PACKED Wh: one base pointer, lane-contiguous 1KB bursts.
// Explicit A/B register ping-pong (depth-1). Epilogue: single-barrier
// kg-reduction (2 partials) through LDS.
// ---------------------------------------------------------------------------
__global__ __launch_bounds__(256, 3) void k_attn(
    const _Float16* __restrict__ Wh_p, const float* __restrict__ fb,
    const float* __restrict__ G, const char* __restrict__ egfg_base,
    float* __restrict__ out)
{
    // XCD-bijective swizzle: 512 = 8 XCD x 64; XCD x owns 2 full bh slices.
    const int orig  = blockIdx.x;
    const int bid   = (orig & 7) * 64 + (orig >> 3);
    const int ntile = bid & 31;
    const int bh    = bid >> 5;
    const int hh    = bh & 7;
    const int b     = bh >> 3;
    const int n0    = ntile * 128;
    const int t     = threadIdx.x;
    const int w     = t >> 6;
    const int l     = t & 63;
    const int kg    = w >> 1;        // 0..1 m-split
    const int wr    = w & 1;         // 0..1 row-split
    const int lr    = l & 15;
    const int lg    = l >> 4;

    const _Float16* Pp  = Wh_p + (size_t)bh * 64 * NN;
    const _Float16* Egp = (const _Float16*)(egfg_base + (size_t)bh * 16384);
    const float     Gv  = G[bh];

    // per-row factors (one of Ef,Ff is exactly 1)
    f16x2 ef2[4], ff2[4];
    #pragma unroll
    for (int rg = 0; rg < 4; rg++) {
        int rn = n0 + wr * 64 + rg * 16 + lr;
        float s  = fb[(size_t)bh * NN + rn] + Gv;
        float t1 = (1.f - ALPHA) * s;
        _Float16 e = (_Float16)exp2f(fminf(t1, 0.f));
        _Float16 f = (_Float16)exp2f(fminf(-t1, 0.f));
        ef2[rg] = (f16x2){e, e};
        ff2[rg] = (f16x2){f, f};
    }
    const f16x2 one2 = (f16x2){(_Float16)1.0f, (_Float16)1.0f};

    f32x4 acc[4][4];
    #pragma unroll
    for (int rg = 0; rg < 4; rg++)
        #pragma unroll
        for (int ct = 0; ct < 4; ct++) acc[rg][ct] = (f32x4){0.f, 0.f, 0.f, 0.f};
    float dsum[4] = {0.f, 0.f, 0.f, 0.f};

    // packed B pointer: one ms-chunk = 4 ct x 64 lanes x 8 halves = 2048 halves
    const _Float16* bp  = Pp + (size_t)kg * 64 * 2048 + (size_t)l * 8;
    const _Float16* ep  = Egp + kg * 2048 + lg * 8;
    const _Float16* epf = ep + NN;

    #define LOADSET(B0,B1,B2,B3,EG,FG)                                          \
        {                                                                        \
            B0 = *(const f16x8*)(bp);         B1 = *(const f16x8*)(bp + 512);    \
            B2 = *(const f16x8*)(bp + 1024);  B3 = *(const f16x8*)(bp + 1536);   \
            EG = *(const f16x8*)ep;           FG = *(const f16x8*)epf;           \
            bp += 2048; ep += 32; epf += 32;                                     \
        }

    #define COMPUTE(B0,B1,B2,B3,EG,FG)                                          \
        {                                                                        \
            _Pragma("unroll")                                                    \
            for (int rg = 0; rg < 4; rg++) {                                     \
                f16x8 af; float ds = dsum[rg];                                   \
                _Pragma("unroll")                                                \
                for (int d = 0; d < 4; d++) {                                    \
                    f16x2 e2 = ((const f16x2*)&(EG))[d];                         \
                    f16x2 f2 = ((const f16x2*)&(FG))[d];                         \
                    f16x2 p2 = __builtin_elementwise_max(e2 * ef2[rg],           \
                                                         f2 * ff2[rg]);          \
                    ((f16x2*)&af)[d] = p2;                                       \
                    ds = dot2acc(p2, one2, ds);                                  \
                }                                                                \
                dsum[rg] = ds;                                                   \
                acc[rg][0] = __builtin_amdgcn_mfma_f32_16x16x32_f16(             \
                    af, B0, acc[rg][0], 0, 0, 0);                                \
                acc[rg][1] = __builtin_amdgcn_mfma_f32_16x16x32_f16(             \
                    af, B1, acc[rg][1], 0, 0, 0);                                \
                acc[rg][2] = __builtin_amdgcn_mfma_f32_16x16x32_f16(             \
                    af, B2, acc[rg][2], 0, 0, 0);                                \
                acc[rg][3] = __builtin_amdgcn_mfma_f32_16x16x32_f16(             \
                    af, B3, acc[rg][3], 0, 0, 0);                                \
            }                                                                    \
        }

    f16x8 a0, a1, a2, a3, ae, az;
    f16x8 c0, c1, c2, c3, ce, cz;
    LOADSET(a0, a1, a2, a3, ae, az);

    // 64 half-steps of 32 m; manual 2x ping-pong so each set's loads are
    // issued one full COMPUTE phase before use.
    #pragma clang loop unroll(disable)
    for (int hs = 0; hs < 64; hs += 2) {
        LOADSET(c0, c1, c2, c3, ce, cz);
        COMPUTE(a0, a1, a2, a3, ae, az);
        if (hs + 2 < 64) LOADSET(a0, a1, a2, a3, ae, az);
        COMPUTE(c0, c1, c2, c3, ce, cz);
    }
    #undef LOADSET
    #undef COMPUTE

    // ---------------- epilogue: kg-reduction (one barrier) ----------------
    __shared__ f32x4 __attribute__((aligned(16))) Rw[2][16 * 64];  // 32 KB
    __shared__ float dnP[256];
    __shared__ float dnS[128];

    // per-row denominator partials (reduce lg groups in-wave)
    #pragma unroll
    for (int rg = 0; rg < 4; rg++) {
        float d = dsum[rg];
        d += __shfl_xor(d, 16, 64);
        d += __shfl_xor(d, 32, 64);
        if (lg == 0) dnP[kg * 128 + wr * 64 + rg * 16 + lr] = d;
    }

    if (kg == 1) {
        #pragma unroll
        for (int rg = 0; rg < 4; rg++)
            #pragma unroll
            for (int ct = 0; ct < 4; ct++)
                Rw[wr][(rg * 4 + ct) * 64 + l] = acc[rg][ct];
    }
    __syncthreads();

    if (kg == 0) {
        // waves 0/1 are kg0-wr0/kg0-wr1; lane l covers row wr*64+l
        dnS[wr * 64 + l] = dnP[wr * 64 + l] + dnP[128 + wr * 64 + l];
        float* outp = out + ((size_t)(b * NN + n0)) * 512 + hh * 64;
        #pragma unroll
        for (int rg = 0; rg < 4; rg++)
            #pragma unroll
            for (int reg = 0; reg < 4; reg++) {
                int row = wr * 64 + rg * 16 + lg * 4 + reg;
                float rinv = 1.0f / dnS[row];
                #pragma unroll
                for (int ct = 0; ct < 4; ct++) {
                    float v = (acc[rg][ct][reg] + Rw[wr][(rg * 4 + ct) * 64 + l][reg])
                              * rinv;
                    v = v > 0.f ? v : (exp2f(v * LOG2E) - 1.f);   // elu
                    outp[(size_t)row * 512 + ct * 16 + lr] = v;
                }
            }
    }
}

// ---------------------------------------------------------------------------
extern "C" void kernel_launch(void* const* d_in, const int* in_sizes, int n_in,
                              void* d_out, int out_size, void* d_ws, size_t ws_size,
                              hipStream_t stream)
{
    const float* hsrc = (const float*)d_in[0];
    const float* W    = (const float*)d_in[1];
    const float* a    = (const float*)d_in[2];
    float* outp       = (float*)d_out;

    const size_t WHT_BYTES = (size_t)NB * NH * 64 * NN * sizeof(_Float16); // 8 MB
    const size_t FB_BYTES  = (size_t)NB * NH * NN * sizeof(float);         // 256 KB
    const size_t GB_BYTES  = (size_t)NB * NH * NN * sizeof(float);         // 256 KB
    const size_t NEED = WHT_BYTES + FB_BYTES + GB_BYTES + 64 * sizeof(float);
    if (ws_size < NEED) return;

    char* ws = (char*)d_ws;
    _Float16* Wh_p = (_Float16*)ws;
    float*    fbuf = (float*)(ws + WHT_BYTES);
    char*     gbase = ws + WHT_BYTES + FB_BYTES;   // g' f32 -> Eg|Fg fp16 (aliased)
    float*    Gmax = (float*)(ws + WHT_BYTES + FB_BYTES + GB_BYTES);

    k_wh  <<<dim3(NB * NH * (NN / 64)),  dim3(256), 0, stream>>>(hsrc, W, a, Wh_p, fbuf, (float*)gbase);
    k_prep<<<dim3(NB * NH),              dim3(256), 0, stream>>>((const float*)gbase, Gmax, gbase);
    k_attn<<<dim3(NB * NH * (NN / 128)), dim3(256), 0, stream>>>(Wh_p, fbuf, Gmax, gbase, outp);
}